// Round 10
// baseline (876.857 us; speedup 1.0000x reference)
//
#include <hip/hip_runtime.h>
#include <hip/hip_cooperative_groups.h>

namespace cg = cooperative_groups;

#define NEG_SLOPE 0.01f

using short8 = __attribute__((ext_vector_type(8))) short;
using f32x4  = __attribute__((ext_vector_type(4))) float;

__device__ inline float b2f(ushort u) {
    union { unsigned u; float f; } x; x.u = ((unsigned)u) << 16; return x.f;
}
__device__ inline ushort f2b(float f) {
    union { float f; unsigned u; } x; x.f = f;
    unsigned r = x.u + 0x7FFFu + ((x.u >> 16) & 1u);  // RNE
    return (ushort)(r >> 16);
}
__device__ inline void gload16(const void* g, void* l) {
    __builtin_amdgcn_global_load_lds((__attribute__((address_space(1))) void*)g,
                                     (__attribute__((address_space(3))) void*)l, 16, 0, 0);
}

// =================== MEGA: all preprocessing + layer-1 aggregation, 1 launch ===================
// Phases: P0 init | P1 count+frontier1 | P2 frontier2 | P3 chunk-sums+dis+wtrans |
//         P4 offset scan (block 0) | P5 chunk-scan writes | P6 filtered fill | P7 aggx.

__global__ __launch_bounds__(256) void mega(
    const float* __restrict__ x, const int* __restrict__ src, const int* __restrict__ dst,
    const int* __restrict__ batch, const float* __restrict__ W1, ushort* __restrict__ W1t,
    const float* __restrict__ W2, ushort* __restrict__ W2t,
    int* __restrict__ cnt, int* __restrict__ flag1, int* __restrict__ flag2,
    int* __restrict__ rootflag, int* __restrict__ picked, float* __restrict__ dis,
    int* __restrict__ rowptr, int* __restrict__ cur, int4* __restrict__ bsums,
    int* __restrict__ counts, int* __restrict__ pos1, int* __restrict__ pos2,
    int* __restrict__ list1, int* __restrict__ list2, int* __restrict__ col,
    ushort* __restrict__ aggXc, int N, int E, int nb) {
    cg::grid_group grid = cg::this_grid();
    __shared__ int l0[256], l1[256], l2[256];
    const int tid = threadIdx.x;
    const int bid = blockIdx.x;
    const int gsz = gridDim.x * 256;
    const int gtid = bid * 256 + tid;
    const int e4 = (E + 3) >> 2;

    // ---- P0: init flags/counters, mark roots, pick root per graph ----
    for (int i = gtid; i < N; i += gsz) {
        cnt[i] = 0;
        flag2[i] = 0;
        int root = (i == 0) || (batch[i] != batch[i - 1]);
        flag1[i] = root;
        rootflag[i] = root;
        if (root) picked[batch[i]] = i;
    }
    grid.sync();

    // ---- P1: degree count + frontier1 (flag1 |= src of root-dst edges) ----
    for (int u = gtid; u < e4; u += gsz) {
        int e0 = u * 4;
        if (e0 + 3 < E) {
            int4 dq = *(const int4*)(dst + e0);
            int r0 = rootflag[dq.x], r1 = rootflag[dq.y], r2 = rootflag[dq.z], r3 = rootflag[dq.w];
            atomicAdd(&cnt[dq.x], 1);
            atomicAdd(&cnt[dq.y], 1);
            atomicAdd(&cnt[dq.z], 1);
            atomicAdd(&cnt[dq.w], 1);
            if (r0 | r1 | r2 | r3) {
                int4 sq = *(const int4*)(src + e0);
                if (r0) flag1[sq.x] = 1;
                if (r1) flag1[sq.y] = 1;
                if (r2) flag1[sq.z] = 1;
                if (r3) flag1[sq.w] = 1;
            }
        } else {
            for (int e = e0; e < E; e++) {
                int d = dst[e];
                atomicAdd(&cnt[d], 1);
                if (rootflag[d]) flag1[src[e]] = 1;
            }
        }
    }
    grid.sync();

    // ---- P2: frontier2 (flag2 = S1 U {src : dst in S1}) ----
    for (int u = gtid; u < e4; u += gsz) {
        int e0 = u * 4;
        if (e0 + 3 < E) {
            int4 dq = *(const int4*)(dst + e0);
            int f0 = flag1[dq.x], f1 = flag1[dq.y], f2 = flag1[dq.z], f3 = flag1[dq.w];
            if (f0 | f1 | f2 | f3) {
                int4 sq = *(const int4*)(src + e0);
                if (f0) flag2[sq.x] = 1;
                if (f1) flag2[sq.y] = 1;
                if (f2) flag2[sq.z] = 1;
                if (f3) flag2[sq.w] = 1;
            }
        } else {
            for (int e = e0; e < E; e++) if (flag1[dst[e]]) flag2[src[e]] = 1;
        }
    }
    for (int i = gtid; i < N; i += gsz) if (flag1[i]) flag2[i] = 1;
    grid.sync();

    // ---- P3: per-chunk totals (masked cnt, flag1, flag2) + dis; idle threads do wtrans ----
    for (int b2 = bid; b2 < nb; b2 += gridDim.x) {
        int base = b2 * 1024 + tid * 4;
        int c[4] = {0,0,0,0}, a1[4] = {0,0,0,0}, a2[4] = {0,0,0,0};
        if (base + 3 < N) {
            int4 q = *(const int4*)(cnt + base); c[0]=q.x; c[1]=q.y; c[2]=q.z; c[3]=q.w;
            int4 u = *(const int4*)(flag1 + base); a1[0]=u.x; a1[1]=u.y; a1[2]=u.z; a1[3]=u.w;
            int4 v = *(const int4*)(flag2 + base); a2[0]=v.x; a2[1]=v.y; a2[2]=v.z; a2[3]=v.w;
        } else {
            for (int i = 0; i < 4; i++) if (base + i < N) {
                c[i] = cnt[base + i]; a1[i] = flag1[base + i]; a2[i] = flag2[base + i];
            }
        }
#pragma unroll
        for (int i = 0; i < 4; i++)
            if (base + i < N) dis[base + i] = rsqrtf((float)c[i] + 1.0f);
        int s0 = 0, s1 = 0, s2 = 0;
#pragma unroll
        for (int i = 0; i < 4; i++) { s0 += a2[i] ? c[i] : 0; s1 += a1[i]; s2 += a2[i]; }
        l0[tid] = s0; l1[tid] = s1; l2[tid] = s2;
        __syncthreads();
        for (int off = 128; off > 0; off >>= 1) {
            if (tid < off) { l0[tid] += l0[tid + off]; l1[tid] += l1[tid + off]; l2[tid] += l2[tid + off]; }
            __syncthreads();
        }
        if (tid == 0) bsums[b2] = make_int4(l0[0], l1[0], l2[0], 0);
        __syncthreads();
    }
    for (int idx = gtid; idx < 98304; idx += gsz) {       // weight transposes
        if (idx < 32768) {                                 // W1t[n][k] = W1[k][n], K=128
            int n = idx >> 7, k = idx & 127;
            W1t[idx] = f2b(W1[k * 256 + n]);
        } else {                                           // W2t[n][k] = W2[k][n], K=256
            int j = idx - 32768;
            int n = j >> 8, k = j & 255;
            W2t[j] = f2b(W2[k * 256 + n]);
        }
    }
    grid.sync();

    // ---- P4: block 0 scans the <=1024 chunk totals -> exclusive offsets + totals ----
    if (bid == 0) {
        int base = tid * 4;
        int v0[4] = {0,0,0,0}, v1[4] = {0,0,0,0}, v2[4] = {0,0,0,0};
        for (int i = 0; i < 4; i++) if (base + i < nb) {
            int4 b = bsums[base + i]; v0[i] = b.x; v1[i] = b.y; v2[i] = b.z;
        }
        int s0 = v0[0]+v0[1]+v0[2]+v0[3];
        int s1 = v1[0]+v1[1]+v1[2]+v1[3];
        int s2 = v2[0]+v2[1]+v2[2]+v2[3];
        l0[tid] = s0; l1[tid] = s1; l2[tid] = s2;
        __syncthreads();
        for (int off = 1; off < 256; off <<= 1) {
            int u0 = (tid >= off) ? l0[tid - off] : 0;
            int u1 = (tid >= off) ? l1[tid - off] : 0;
            int u2 = (tid >= off) ? l2[tid - off] : 0;
            __syncthreads();
            l0[tid] += u0; l1[tid] += u1; l2[tid] += u2;
            __syncthreads();
        }
        int run0 = l0[tid] - s0, run1 = l1[tid] - s1, run2 = l2[tid] - s2;
        for (int i = 0; i < 4; i++) {
            if (base + i < nb) bsums[base + i] = make_int4(run0, run1, run2, 0);
            run0 += v0[i]; run1 += v1[i]; run2 += v2[i];
        }
        if (tid == 255) {
            counts[0] = l1[255];   // M1
            counts[1] = l2[255];   // M2
            rowptr[N] = l0[255];   // total kept edges
        }
    }
    grid.sync();

    // ---- P5: per-chunk scan + write rowptr/cur/pos/list ----
    for (int b2 = bid; b2 < nb; b2 += gridDim.x) {
        int base = b2 * 1024 + tid * 4;
        int c[4] = {0,0,0,0}, a1[4] = {0,0,0,0}, a2[4] = {0,0,0,0};
        if (base + 3 < N) {
            int4 q = *(const int4*)(cnt + base); c[0]=q.x; c[1]=q.y; c[2]=q.z; c[3]=q.w;
            int4 u = *(const int4*)(flag1 + base); a1[0]=u.x; a1[1]=u.y; a1[2]=u.z; a1[3]=u.w;
            int4 v = *(const int4*)(flag2 + base); a2[0]=v.x; a2[1]=v.y; a2[2]=v.z; a2[3]=v.w;
        } else {
            for (int i = 0; i < 4; i++) if (base + i < N) {
                c[i] = cnt[base + i]; a1[i] = flag1[base + i]; a2[i] = flag2[base + i];
            }
        }
        int m[4];
#pragma unroll
        for (int i = 0; i < 4; i++) m[i] = a2[i] ? c[i] : 0;
        int s0 = m[0]+m[1]+m[2]+m[3];
        int s1 = a1[0]+a1[1]+a1[2]+a1[3];
        int s2 = a2[0]+a2[1]+a2[2]+a2[3];
        l0[tid] = s0; l1[tid] = s1; l2[tid] = s2;
        __syncthreads();
        for (int off = 1; off < 256; off <<= 1) {
            int u0 = (tid >= off) ? l0[tid - off] : 0;
            int u1 = (tid >= off) ? l1[tid - off] : 0;
            int u2 = (tid >= off) ? l2[tid - off] : 0;
            __syncthreads();
            l0[tid] += u0; l1[tid] += u1; l2[tid] += u2;
            __syncthreads();
        }
        int4 bs = bsums[b2];
        int run0 = bs.x + l0[tid] - s0;
        int run1 = bs.y + l1[tid] - s1;
        int run2 = bs.z + l2[tid] - s2;
#pragma unroll
        for (int i = 0; i < 4; i++) {
            if (base + i < N) {
                rowptr[base + i] = run0;
                cur[base + i] = run0;
                if (a1[i]) { pos1[base + i] = run1; list1[run1] = base + i; }
                if (a2[i]) { pos2[base + i] = run2; list2[run2] = base + i; }
            }
            run0 += m[i]; run1 += a1[i]; run2 += a2[i];
        }
        __syncthreads();
    }
    grid.sync();

    // ---- P6: filtered CSR fill (only edges with dst in S2) ----
    for (int u = gtid; u < e4; u += gsz) {
        int e0 = u * 4;
        if (e0 + 3 < E) {
            int4 dq = *(const int4*)(dst + e0);
            int f0 = flag2[dq.x], f1 = flag2[dq.y], f2 = flag2[dq.z], f3 = flag2[dq.w];
            if (f0 | f1 | f2 | f3) {
                int4 sq = *(const int4*)(src + e0);
                if (f0) col[atomicAdd(&cur[dq.x], 1)] = sq.x;
                if (f1) col[atomicAdd(&cur[dq.y], 1)] = sq.y;
                if (f2) col[atomicAdd(&cur[dq.z], 1)] = sq.z;
                if (f3) col[atomicAdd(&cur[dq.w], 1)] = sq.w;
            }
        } else {
            for (int e = e0; e < E; e++) {
                int d = dst[e];
                if (flag2[d]) col[atomicAdd(&cur[d], 1)] = src[e];
            }
        }
    }
    grid.sync();

    // ---- P7: layer-1 aggregation on S2 from f32 x ----
    {
        const int M2 = counts[1];
        int wave = gtid >> 6;
        int lane = tid & 63;
        int li = lane & 31, sub = lane >> 5;
        int stride = gridDim.x * 8;   // 4 waves/block * 2 rows/wave
        const float* xp = x + li * 4;
        for (int p = wave * 2 + sub; p < M2; p += stride) {
            int node = list2[p];
            float di = dis[node];
            float4 sv = *(const float4*)(xp + (size_t)node * 128);
            float a0 = di * sv.x, a1 = di * sv.y, a2 = di * sv.z, a3 = di * sv.w;
            int e = rowptr[node], e1 = rowptr[node + 1];
            for (; e + 2 <= e1; e += 2) {
                int s0 = col[e], s1 = col[e + 1];
                float w0 = dis[s0], w1 = dis[s1];
                float4 v0 = *(const float4*)(xp + (size_t)s0 * 128);
                float4 v1 = *(const float4*)(xp + (size_t)s1 * 128);
                a0 += w0 * v0.x + w1 * v1.x;
                a1 += w0 * v0.y + w1 * v1.y;
                a2 += w0 * v0.z + w1 * v1.z;
                a3 += w0 * v0.w + w1 * v1.w;
            }
            if (e < e1) {
                int s = col[e];
                float w = dis[s];
                float4 v = *(const float4*)(xp + (size_t)s * 128);
                a0 += w * v.x; a1 += w * v.y; a2 += w * v.z; a3 += w * v.w;
            }
            ushort4 o;
            o.x = f2b(di * a0); o.y = f2b(di * a1); o.z = f2b(di * a2); o.w = f2b(di * a3);
            *(ushort4*)(aggXc + (size_t)p * 128 + li * 4) = o;
        }
    }
}

// =================== compact MFMA GEMM (layer 1): h1c = f(aggXc @ W1t^T) ===================

template <int K>
__global__ __launch_bounds__(512) void gemm_c(const ushort* __restrict__ A,
                                              const ushort* __restrict__ Bt,
                                              const float* __restrict__ bias,
                                              const float* __restrict__ dis,
                                              const int* __restrict__ list,
                                              const int* __restrict__ counts, int which,
                                              ushort* __restrict__ C) {
    __shared__ ushort As[128 * 64];   // 16 KB
    __shared__ ushort Bs[256 * 64];   // 32 KB
    const int M = counts[which];
    const int t = threadIdx.x;
    const int lane = t & 63;
    const int w = t >> 6;
    const int wm = w >> 2, wn = w & 3;

    for (int tile = blockIdx.x; tile * 128 < M; tile += gridDim.x) {
        const int row0 = tile * 128;
        f32x4 acc[4][4] = {};

        for (int kt = 0; kt < K / 64; kt++) {
#pragma unroll
            for (int it = 0; it < 2; it++) {
                int q = it * 512 + t;
                int r = q >> 3, c = q & 7;
                int cs = c ^ (r & 7);
                int ga = min(row0 + r, M - 1);
                gload16(A + (size_t)ga * K + kt * 64 + cs * 8, &As[q * 8]);
            }
#pragma unroll
            for (int it = 0; it < 4; it++) {
                int q = it * 512 + t;
                int r = q >> 3, c = q & 7;
                int cs = c ^ (r & 7);
                gload16(Bt + (size_t)r * K + kt * 64 + cs * 8, &Bs[q * 8]);
            }
            __syncthreads();
#pragma unroll
            for (int ks = 0; ks < 2; ks++) {
                short8 a[4], b[4];
                int cc = ks * 4 + (lane >> 4);
#pragma unroll
                for (int m = 0; m < 4; m++) {
                    int R = wm * 64 + m * 16 + (lane & 15);
                    a[m] = *(const short8*)&As[R * 64 + ((cc ^ (R & 7)) * 8)];
                }
#pragma unroll
                for (int n = 0; n < 4; n++) {
                    int R = wn * 64 + n * 16 + (lane & 15);
                    b[n] = *(const short8*)&Bs[R * 64 + ((cc ^ (R & 7)) * 8)];
                }
#pragma unroll
                for (int m = 0; m < 4; m++)
#pragma unroll
                    for (int n = 0; n < 4; n++)
                        acc[m][n] = __builtin_amdgcn_mfma_f32_16x16x32_bf16(a[m], b[n], acc[m][n], 0, 0, 0);
            }
            __syncthreads();
        }

#pragma unroll
        for (int m = 0; m < 4; m++) {
#pragma unroll
            for (int j = 0; j < 4; j++) {
                int grow = row0 + wm * 64 + m * 16 + (lane >> 4) * 4 + j;
                if (grow >= M) continue;
                float dr = dis[list[grow]];
#pragma unroll
                for (int n = 0; n < 4; n++) {
                    int gcol = wn * 64 + n * 16 + (lane & 15);
                    float v = acc[m][n][j] + bias[gcol];
                    v = v > 0.f ? v : NEG_SLOPE * v;
                    C[(size_t)grow * 256 + gcol] = f2b(v * dr);
                }
            }
        }
    }
}

// =================== TAIL: agg2 -> gemm2(K=256) -> final, 1 cooperative launch ===================

__global__ __launch_bounds__(512) void tail(
    const ushort* __restrict__ h1c, const float* __restrict__ dis,
    const int* __restrict__ rowptr, const int* __restrict__ col,
    const int* __restrict__ list1, const int* __restrict__ pos2,
    const int* __restrict__ counts, ushort* __restrict__ agg1c,
    const ushort* __restrict__ W2t, const float* __restrict__ b2,
    ushort* __restrict__ h2c, const int* __restrict__ picked,
    const int* __restrict__ pos1, const float* __restrict__ W3,
    const float* __restrict__ b3, float* __restrict__ out, int G) {
    cg::grid_group grid = cg::this_grid();
    __shared__ ushort As[128 * 64];
    __shared__ ushort Bs[256 * 64];
    __shared__ float aggf[256];
    __shared__ float redf[256];
    const int t = threadIdx.x;
    const int bid = blockIdx.x;
    const int lane = t & 63;
    const int w = t >> 6;
    const int M1 = counts[0];

    // ---- T1: layer-2 aggregation on S1 (h1c rows via pos2) ----
    {
        int wave = bid * 8 + w;
        int li = lane & 31, sub = lane >> 5;
        int stride = gridDim.x * 16;
        const ushort* hp = h1c + (size_t)li * 8;
        for (int p = wave * 2 + sub; p < M1; p += stride) {
            int i = list1[p];
            float di = dis[i];
            float a[8];
            {
                short8 v = *(const short8*)(hp + (size_t)pos2[i] * 256);
#pragma unroll
                for (int j = 0; j < 8; j++) a[j] = b2f((ushort)v[j]);
            }
            int e1 = rowptr[i + 1];
            for (int e = rowptr[i]; e < e1; e++) {
                short8 v = *(const short8*)(hp + (size_t)pos2[col[e]] * 256);
#pragma unroll
                for (int j = 0; j < 8; j++) a[j] += b2f((ushort)v[j]);
            }
            short8 o;
#pragma unroll
            for (int j = 0; j < 8; j++) o[j] = (short)f2b(di * a[j]);
            *(short8*)(agg1c + (size_t)p * 256 + li * 8) = o;
        }
    }
    grid.sync();

    // ---- T2: gemm K=256: h2c = bf16( dis * leaky(agg1c @ W2t^T + b2) ) ----
    {
        const int wm = w >> 2, wn = w & 3;
        for (int tile = bid; tile * 128 < M1; tile += gridDim.x) {
            const int row0 = tile * 128;
            f32x4 acc[4][4] = {};
            for (int kt = 0; kt < 4; kt++) {
#pragma unroll
                for (int it = 0; it < 2; it++) {
                    int q = it * 512 + t;
                    int r = q >> 3, c = q & 7;
                    int cs = c ^ (r & 7);
                    int ga = min(row0 + r, M1 - 1);
                    gload16(agg1c + (size_t)ga * 256 + kt * 64 + cs * 8, &As[q * 8]);
                }
#pragma unroll
                for (int it = 0; it < 4; it++) {
                    int q = it * 512 + t;
                    int r = q >> 3, c = q & 7;
                    int cs = c ^ (r & 7);
                    gload16(W2t + (size_t)r * 256 + kt * 64 + cs * 8, &Bs[q * 8]);
                }
                __syncthreads();
#pragma unroll
                for (int ks = 0; ks < 2; ks++) {
                    short8 a[4], b[4];
                    int cc = ks * 4 + (lane >> 4);
#pragma unroll
                    for (int m = 0; m < 4; m++) {
                        int R = wm * 64 + m * 16 + (lane & 15);
                        a[m] = *(const short8*)&As[R * 64 + ((cc ^ (R & 7)) * 8)];
                    }
#pragma unroll
                    for (int n = 0; n < 4; n++) {
                        int R = wn * 64 + n * 16 + (lane & 15);
                        b[n] = *(const short8*)&Bs[R * 64 + ((cc ^ (R & 7)) * 8)];
                    }
#pragma unroll
                    for (int m = 0; m < 4; m++)
#pragma unroll
                        for (int n = 0; n < 4; n++)
                            acc[m][n] = __builtin_amdgcn_mfma_f32_16x16x32_bf16(a[m], b[n], acc[m][n], 0, 0, 0);
                }
                __syncthreads();
            }
#pragma unroll
            for (int m = 0; m < 4; m++) {
#pragma unroll
                for (int j = 0; j < 4; j++) {
                    int grow = row0 + wm * 64 + m * 16 + (lane >> 4) * 4 + j;
                    if (grow >= M1) continue;
                    float dr = dis[list1[grow]];
#pragma unroll
                    for (int n = 0; n < 4; n++) {
                        int gcol = wn * 64 + n * 16 + (lane & 15);
                        float v = acc[m][n][j] + b2[gcol];
                        v = v > 0.f ? v : NEG_SLOPE * v;
                        h2c[(size_t)grow * 256 + gcol] = f2b(v * dr);
                    }
                }
            }
        }
    }
    grid.sync();

    // ---- T3: final per graph: out = (dis*(sum h2c at root)) @ W3 + b3 ----
    for (int g = bid; g < G; g += gridDim.x) {
        if (t < 256) {
            int i = picked[g];
            float di = dis[i];
            float a = b2f(h2c[(size_t)pos1[i] * 256 + t]);
            int e1 = rowptr[i + 1];
            for (int e = rowptr[i]; e < e1; e++)
                a += b2f(h2c[(size_t)pos1[col[e]] * 256 + t]);
            aggf[t] = di * a;
        }
        __syncthreads();
        if (t < 256) {
            int c = t & 15, seg = t >> 4;
            float p = 0.f;
#pragma unroll
            for (int kk = 0; kk < 16; kk++) {
                int k = seg * 16 + kk;
                p += aggf[k] * W3[k * 16 + c];
            }
            redf[t] = p;
        }
        __syncthreads();
        if (t < 16) {
            float s = 0.f;
#pragma unroll
            for (int ss = 0; ss < 16; ss++) s += redf[ss * 16 + t];
            out[g * 16 + t] = s + b3[t];
        }
        __syncthreads();
    }
}

// =================== launch ===================

extern "C" void kernel_launch(void* const* d_in, const int* in_sizes, int n_in,
                              void* d_out, int out_size, void* d_ws, size_t ws_size,
                              hipStream_t stream) {
    const float* x   = (const float*)d_in[0];
    const int* ei    = (const int*)d_in[1];
    const int* batch = (const int*)d_in[2];
    const float* W1  = (const float*)d_in[3];
    const float* b1  = (const float*)d_in[4];
    const float* W2  = (const float*)d_in[5];
    const float* b2  = (const float*)d_in[6];
    const float* W3  = (const float*)d_in[7];
    const float* b3  = (const float*)d_in[8];
    float* outp = (float*)d_out;

    const int IN = 128, H = 256, OUT = 16;
    int N = in_sizes[0] / IN;
    int E = in_sizes[1] / 2;
    int G = out_size / OUT;
    const int* srcp = ei;
    const int* dstp = ei + E;

    char* p = (char*)d_ws;
    auto carve = [&](size_t bytes) {
        char* q = p;
        p += (bytes + 255) & ~(size_t)255;
        return q;
    };
    int*    cnt      = (int*)carve((size_t)N * 4);
    int*    flag1    = (int*)carve((size_t)N * 4);
    int*    flag2    = (int*)carve((size_t)N * 4);
    int*    rootflag = (int*)carve((size_t)N * 4);
    float*  dis    = (float*)carve((size_t)N * 4);
    int*    rowptr = (int*)carve(((size_t)N + 1) * 4);
    int*    cur    = (int*)carve((size_t)N * 4);
    int4*   tbsums = (int4*)carve(1024 * 16);
    int*    counts = (int*)carve(256);
    int*    picked = (int*)carve((size_t)G * 4);
    int*    pos1   = (int*)carve((size_t)N * 4);
    int*    pos2   = (int*)carve((size_t)N * 4);
    int*    list1  = (int*)carve((size_t)N * 4);
    int*    list2  = (int*)carve((size_t)N * 4);
    int*    col    = (int*)carve((size_t)E * 4);
    ushort* W1t    = (ushort*)carve((size_t)256 * 128 * 2);
    ushort* W2t    = (ushort*)carve((size_t)256 * 256 * 2);
    ushort* RA     = (ushort*)carve((size_t)N * H * 2);  // aggXc, then agg1c
    ushort* RB     = (ushort*)carve((size_t)N * H * 2);  // h1c, then h2c

    ushort* aggXc = RA;   // [M2][128]
    ushort* agg1c = RA;   // [M1][256] (aggXc dead after gemm1)
    ushort* h1c   = RB;   // [M2][256]
    ushort* h2c   = RB;   // [M1][256] (h1c dead after T1)

    int nb = (N + 1023) / 1024;

    // 1) mega: preprocessing + layer-1 aggregation (cooperative, 7 grid syncs)
    void* margs[] = { (void*)&x, (void*)&srcp, (void*)&dstp, (void*)&batch,
                      (void*)&W1, (void*)&W1t, (void*)&W2, (void*)&W2t,
                      (void*)&cnt, (void*)&flag1, (void*)&flag2, (void*)&rootflag,
                      (void*)&picked, (void*)&dis, (void*)&rowptr, (void*)&cur,
                      (void*)&tbsums, (void*)&counts, (void*)&pos1, (void*)&pos2,
                      (void*)&list1, (void*)&list2, (void*)&col, (void*)&aggXc,
                      (void*)&N, (void*)&E, (void*)&nb };
    hipLaunchCooperativeKernel(mega, dim3(1024), dim3(256), margs, 0, stream);

    // 2) layer-1 GEMM: h1c = dis*leaky(aggXc @ W1 + b1), rows = S2
    gemm_c<128><<<128, 512, 0, stream>>>(aggXc, W1t, b1, dis, list2, counts, 1, h1c);

    // 3) tail: agg2 -> gemm2 -> final (cooperative, 2 grid syncs)
    void* targs[] = { (void*)&h1c, (void*)&dis, (void*)&rowptr, (void*)&col,
                      (void*)&list1, (void*)&pos2, (void*)&counts, (void*)&agg1c,
                      (void*)&W2t, (void*)&b2, (void*)&h2c, (void*)&picked,
                      (void*)&pos1, (void*)&W3, (void*)&b3, (void*)&outp, (void*)&G };
    hipLaunchCooperativeKernel(tail, dim3(64), dim3(512), targs, 0, stream);
}

// Round 11
// 130.939 us; speedup vs baseline: 6.6967x; 6.6967x over previous
//
#include <hip/hip_runtime.h>

#define NEG_SLOPE 0.01f

using short8 = __attribute__((ext_vector_type(8))) short;
using f32x4  = __attribute__((ext_vector_type(4))) float;

__device__ inline float b2f(ushort u) {
    union { unsigned u; float f; } x; x.u = ((unsigned)u) << 16; return x.f;
}
__device__ inline ushort f2b(float f) {
    union { float f; unsigned u; } x; x.f = f;
    unsigned r = x.u + 0x7FFFu + ((x.u >> 16) & 1u);  // RNE
    return (ushort)(r >> 16);
}
__device__ inline void gload16(const void* g, void* l) {
    __builtin_amdgcn_global_load_lds((__attribute__((address_space(1))) void*)g,
                                     (__attribute__((address_space(3))) void*)l, 16, 0, 0);
}

// ---------------- init: zero flags/counters/scan-slots, mark roots, pick roots ----------------

__global__ void init_kernel(const int* __restrict__ batch, int* __restrict__ cnt,
                            int* __restrict__ flag1, int* __restrict__ flag2,
                            int* __restrict__ rootflag, int* __restrict__ picked,
                            int4* __restrict__ aggslot, int N) {
    int i = blockIdx.x * blockDim.x + threadIdx.x;
    if (i < 1024) aggslot[i] = make_int4(0, 0, 0, 0);
    if (i >= N) return;
    cnt[i] = 0;
    int root = (i == 0) || (batch[i] != batch[i - 1]);
    flag1[i] = root;   // roots are in S1
    flag2[i] = 0;
    rootflag[i] = root;
    if (root) picked[batch[i]] = i;
}

// ---------------- E-pass 1: degree count + frontier1 (flag1 |= src of root-dst edges) ----------------

__global__ void count_f1(const int* __restrict__ src, const int* __restrict__ dst,
                         const int* __restrict__ rootflag, int* __restrict__ cnt,
                         int* __restrict__ flag1, int E) {
    int i = blockIdx.x * blockDim.x + threadIdx.x;
    int e0 = i * 4;
    if (e0 + 3 < E) {
        int4 dq = *(const int4*)(dst + e0);
        int r0 = rootflag[dq.x], r1 = rootflag[dq.y], r2 = rootflag[dq.z], r3 = rootflag[dq.w];
        atomicAdd(&cnt[dq.x], 1);
        atomicAdd(&cnt[dq.y], 1);
        atomicAdd(&cnt[dq.z], 1);
        atomicAdd(&cnt[dq.w], 1);
        if (r0 | r1 | r2 | r3) {
            int4 sq = *(const int4*)(src + e0);
            if (r0) flag1[sq.x] = 1;
            if (r1) flag1[sq.y] = 1;
            if (r2) flag1[sq.z] = 1;
            if (r3) flag1[sq.w] = 1;
        }
    } else if (e0 < E) {
        for (int e = e0; e < E; e++) {
            int d = dst[e];
            atomicAdd(&cnt[d], 1);
            if (rootflag[d]) flag1[src[e]] = 1;
        }
    }
}

// ---------------- E-pass 2: frontier2 (flag2 = S1 U {src : dst in S1}) ----------------

__global__ void frontier2v(const int* __restrict__ src, const int* __restrict__ dst,
                           const int* __restrict__ flag1, int* __restrict__ flag2,
                           int E, int N) {
    int i = blockIdx.x * blockDim.x + threadIdx.x;
    int e0 = i * 4;
    if (e0 + 3 < E) {
        int4 dq = *(const int4*)(dst + e0);
        int f0 = flag1[dq.x], f1 = flag1[dq.y], f2 = flag1[dq.z], f3 = flag1[dq.w];
        if (f0 | f1 | f2 | f3) {
            int4 sq = *(const int4*)(src + e0);
            if (f0) flag2[sq.x] = 1;
            if (f1) flag2[sq.y] = 1;
            if (f2) flag2[sq.z] = 1;
            if (f3) flag2[sq.w] = 1;
        }
    } else if (e0 < E) {
        for (int e = e0; e < E; e++) if (flag1[dst[e]]) flag2[src[e]] = 1;
    }
    if (i < N && flag1[i]) flag2[i] = 1;
}

// ---------------- single-kernel triple scan (all-predecessor wave-parallel lookback) ----------------
// Channels: (masked cnt, flag1, flag2). Fused: dis, rowptr/cur, pos1/2, list1/2, counts, wtrans.
// Cross-block communication is ONLY via device-scope atomics on aggslot (coherent, no L2 flush).

__global__ __launch_bounds__(256) void scan_one(
    const int* __restrict__ cnt, const int* __restrict__ f1, const int* __restrict__ f2,
    int4* __restrict__ aggslot, float* __restrict__ dis,
    int* __restrict__ rowptr, int* __restrict__ cur,
    int* __restrict__ pos1, int* __restrict__ pos2,
    int* __restrict__ list1, int* __restrict__ list2,
    int* __restrict__ counts, int N, int nb,
    const float* __restrict__ W1, ushort* __restrict__ W1t,
    const float* __restrict__ W2, ushort* __restrict__ W2t) {
    __shared__ int l0[256], l1[256], l2[256];
    __shared__ int baseS[3];
    const int b = blockIdx.x, t = threadIdx.x;
    const int base = b * 1024 + t * 4;

    // load 4 elems of each channel
    int c[4] = {0,0,0,0}, a1[4] = {0,0,0,0}, a2[4] = {0,0,0,0};
    if (base + 3 < N) {
        int4 q = *(const int4*)(cnt + base); c[0]=q.x; c[1]=q.y; c[2]=q.z; c[3]=q.w;
        int4 u = *(const int4*)(f1 + base);  a1[0]=u.x; a1[1]=u.y; a1[2]=u.z; a1[3]=u.w;
        int4 v = *(const int4*)(f2 + base);  a2[0]=v.x; a2[1]=v.y; a2[2]=v.z; a2[3]=v.w;
    } else {
        for (int i = 0; i < 4; i++) if (base + i < N) {
            c[i] = cnt[base + i]; a1[i] = f1[base + i]; a2[i] = f2[base + i];
        }
    }
#pragma unroll
    for (int i = 0; i < 4; i++)
        if (base + i < N) dis[base + i] = rsqrtf((float)c[i] + 1.0f);

    int m[4];
#pragma unroll
    for (int i = 0; i < 4; i++) m[i] = a2[i] ? c[i] : 0;
    int ts0 = m[0] + m[1] + m[2] + m[3];
    int ts1 = a1[0] + a1[1] + a1[2] + a1[3];
    int ts2 = a2[0] + a2[1] + a2[2] + a2[3];
    l0[t] = ts0; l1[t] = ts1; l2[t] = ts2;
    __syncthreads();
    // inclusive block scan (Hillis-Steele)
    for (int off = 1; off < 256; off <<= 1) {
        int u0 = (t >= off) ? l0[t - off] : 0;
        int u1 = (t >= off) ? l1[t - off] : 0;
        int u2 = (t >= off) ? l2[t - off] : 0;
        __syncthreads();
        l0[t] += u0; l1[t] += u1; l2[t] += u2;
        __syncthreads();
    }

    // publish this block's aggregate (device-scope atomics; flag w=1 is the release)
    if (t == 0) {
        __hip_atomic_store(&aggslot[b].x, l0[255], __ATOMIC_RELAXED, __HIP_MEMORY_SCOPE_AGENT);
        __hip_atomic_store(&aggslot[b].y, l1[255], __ATOMIC_RELAXED, __HIP_MEMORY_SCOPE_AGENT);
        __hip_atomic_store(&aggslot[b].z, l2[255], __ATOMIC_RELAXED, __HIP_MEMORY_SCOPE_AGENT);
        __hip_atomic_store(&aggslot[b].w, 1, __ATOMIC_RELEASE, __HIP_MEMORY_SCOPE_AGENT);
    }

    // wave0: sum ALL predecessor aggregates (wave-parallel spin; <=2 rounds at nb<=128)
    if (t < 64) {
        int g0 = 0, g1 = 0, g2 = 0;
        for (int w0 = 0; w0 < b; w0 += 64) {
            int idx = w0 + t;
            if (idx < b) {
                while (__hip_atomic_load(&aggslot[idx].w, __ATOMIC_ACQUIRE,
                                         __HIP_MEMORY_SCOPE_AGENT) == 0) {
                    __builtin_amdgcn_s_sleep(1);
                }
                g0 += __hip_atomic_load(&aggslot[idx].x, __ATOMIC_RELAXED, __HIP_MEMORY_SCOPE_AGENT);
                g1 += __hip_atomic_load(&aggslot[idx].y, __ATOMIC_RELAXED, __HIP_MEMORY_SCOPE_AGENT);
                g2 += __hip_atomic_load(&aggslot[idx].z, __ATOMIC_RELAXED, __HIP_MEMORY_SCOPE_AGENT);
            }
        }
#pragma unroll
        for (int s = 1; s < 64; s <<= 1) {
            g0 += __shfl_xor(g0, s, 64);
            g1 += __shfl_xor(g1, s, 64);
            g2 += __shfl_xor(g2, s, 64);
        }
        if (t == 0) { baseS[0] = g0; baseS[1] = g1; baseS[2] = g2; }
    }
    __syncthreads();

    int run0 = baseS[0] + l0[t] - ts0;
    int run1 = baseS[1] + l1[t] - ts1;
    int run2 = baseS[2] + l2[t] - ts2;
#pragma unroll
    for (int i = 0; i < 4; i++) {
        if (base + i < N) {
            rowptr[base + i] = run0;
            cur[base + i] = run0;
            if (a1[i]) { pos1[base + i] = run1; list1[run1] = base + i; }
            if (a2[i]) { pos2[base + i] = run2; list2[run2] = base + i; }
        }
        run0 += m[i]; run1 += a1[i]; run2 += a2[i];
    }
    if (b == nb - 1 && t == 255) {
        counts[0] = baseS[1] + l1[255];   // M1
        counts[1] = baseS[2] + l2[255];   // M2
        rowptr[N] = baseS[0] + l0[255];   // total kept edges
    }

    // fused weight transposes (independent work)
    for (int idx = b * 256 + t; idx < 98304; idx += gridDim.x * 256) {
        if (idx < 32768) {                   // W1t[n][k] = W1[k][n], K=128
            int n = idx >> 7, k = idx & 127;
            W1t[idx] = f2b(W1[k * 256 + n]);
        } else {                             // W2t[n][k] = W2[k][n], K=256
            int j = idx - 32768;
            int n = j >> 8, k = j & 255;
            W2t[j] = f2b(W2[k * 256 + n]);
        }
    }
}

// ---------------- E-pass 3: filtered CSR fill (only edges whose dst is in S2) ----------------

__global__ void fill_fv(const int* __restrict__ src, const int* __restrict__ dst,
                        const int* __restrict__ flag2, int* __restrict__ cur,
                        int* __restrict__ col, int E) {
    int i = blockIdx.x * blockDim.x + threadIdx.x;
    int e0 = i * 4;
    if (e0 + 3 < E) {
        int4 dq = *(const int4*)(dst + e0);
        int f0 = flag2[dq.x], f1 = flag2[dq.y], f2 = flag2[dq.z], f3 = flag2[dq.w];
        if (f0 | f1 | f2 | f3) {
            int4 sq = *(const int4*)(src + e0);
            if (f0) col[atomicAdd(&cur[dq.x], 1)] = sq.x;
            if (f1) col[atomicAdd(&cur[dq.y], 1)] = sq.y;
            if (f2) col[atomicAdd(&cur[dq.z], 1)] = sq.z;
            if (f3) col[atomicAdd(&cur[dq.w], 1)] = sq.w;
        }
    } else if (e0 < E) {
        for (int e = e0; e < E; e++) {
            int d = dst[e];
            if (flag2[d]) col[atomicAdd(&cur[d], 1)] = src[e];
        }
    }
}

// ---------------- layer-1 aggregation on S2 (compact): from f32 x directly ----------------

__global__ __launch_bounds__(256) void aggx_c(const float* __restrict__ x,
                                              const float* __restrict__ dis,
                                              const int* __restrict__ rowptr,
                                              const int* __restrict__ col,
                                              const int* __restrict__ list2,
                                              const int* __restrict__ counts,
                                              ushort* __restrict__ aggXc) {
    const int M2 = counts[1];
    int wave = blockIdx.x * 4 + (threadIdx.x >> 6);
    int lane = threadIdx.x & 63;
    int li = lane & 31, sub = lane >> 5;
    int stride = gridDim.x * 8;  // 2 rows/wave
    const float* xp = x + li * 4;
    for (int p = wave * 2 + sub; p < M2; p += stride) {
        int node = list2[p];
        float di = dis[node];
        float4 sv = *(const float4*)(xp + (size_t)node * 128);
        float a0 = di * sv.x, a1 = di * sv.y, a2 = di * sv.z, a3 = di * sv.w;
        int e = rowptr[node], e1 = rowptr[node + 1];
        for (; e + 2 <= e1; e += 2) {
            int s0 = col[e], s1 = col[e + 1];
            float w0 = dis[s0], w1 = dis[s1];
            float4 v0 = *(const float4*)(xp + (size_t)s0 * 128);
            float4 v1 = *(const float4*)(xp + (size_t)s1 * 128);
            a0 += w0 * v0.x + w1 * v1.x;
            a1 += w0 * v0.y + w1 * v1.y;
            a2 += w0 * v0.z + w1 * v1.z;
            a3 += w0 * v0.w + w1 * v1.w;
        }
        if (e < e1) {
            int s = col[e];
            float w = dis[s];
            float4 v = *(const float4*)(xp + (size_t)s * 128);
            a0 += w * v.x; a1 += w * v.y; a2 += w * v.z; a3 += w * v.w;
        }
        ushort4 o;
        o.x = f2b(di * a0); o.y = f2b(di * a1); o.z = f2b(di * a2); o.w = f2b(di * a3);
        *(ushort4*)(aggXc + (size_t)p * 128 + li * 4) = o;
    }
}

// ---------------- layer-2 aggregation on S1 (compact), h1c indexed via pos2 ----------------

__global__ __launch_bounds__(256) void agg2_c(const ushort* __restrict__ h1c,
                                              const float* __restrict__ dis,
                                              const int* __restrict__ rowptr,
                                              const int* __restrict__ col,
                                              const int* __restrict__ list1,
                                              const int* __restrict__ pos2,
                                              const int* __restrict__ counts,
                                              ushort* __restrict__ agg1c) {
    const int M1 = counts[0];
    int wave = blockIdx.x * 4 + (threadIdx.x >> 6);
    int lane = threadIdx.x & 63;
    int li = lane & 31, sub = lane >> 5;
    int stride = gridDim.x * 8;
    const ushort* hp = h1c + (size_t)li * 8;
    for (int p = wave * 2 + sub; p < M1; p += stride) {
        int i = list1[p];
        float di = dis[i];
        float a[8];
        {
            short8 v = *(const short8*)(hp + (size_t)pos2[i] * 256);
#pragma unroll
            for (int j = 0; j < 8; j++) a[j] = b2f((ushort)v[j]);
        }
        int e1 = rowptr[i + 1];
        for (int e = rowptr[i]; e < e1; e++) {
            short8 v = *(const short8*)(hp + (size_t)pos2[col[e]] * 256);
#pragma unroll
            for (int j = 0; j < 8; j++) a[j] += b2f((ushort)v[j]);
        }
        short8 o;
#pragma unroll
        for (int j = 0; j < 8; j++) o[j] = (short)f2b(di * a[j]);
        *(short8*)(agg1c + (size_t)p * 256 + li * 8) = o;
    }
}

// ---------------- compact MFMA GEMM: C[M x 256] = bf16( dis[list[row]] * leaky(A @ Bt^T + bias) ) ----------------

template <int K>
__global__ __launch_bounds__(512) void gemm_c(const ushort* __restrict__ A,
                                              const ushort* __restrict__ Bt,
                                              const float* __restrict__ bias,
                                              const float* __restrict__ dis,
                                              const int* __restrict__ list,
                                              const int* __restrict__ counts, int which,
                                              ushort* __restrict__ C) {
    __shared__ ushort As[128 * 64];   // 16 KB
    __shared__ ushort Bs[256 * 64];   // 32 KB
    const int M = counts[which];
    const int t = threadIdx.x;
    const int lane = t & 63;
    const int w = t >> 6;
    const int wm = w >> 2, wn = w & 3;

    for (int tile = blockIdx.x; tile * 128 < M; tile += gridDim.x) {
        const int row0 = tile * 128;
        f32x4 acc[4][4] = {};

        for (int kt = 0; kt < K / 64; kt++) {
#pragma unroll
            for (int it = 0; it < 2; it++) {
                int q = it * 512 + t;
                int r = q >> 3, c = q & 7;
                int cs = c ^ (r & 7);
                int ga = min(row0 + r, M - 1);
                gload16(A + (size_t)ga * K + kt * 64 + cs * 8, &As[q * 8]);
            }
#pragma unroll
            for (int it = 0; it < 4; it++) {
                int q = it * 512 + t;
                int r = q >> 3, c = q & 7;
                int cs = c ^ (r & 7);
                gload16(Bt + (size_t)r * K + kt * 64 + cs * 8, &Bs[q * 8]);
            }
            __syncthreads();
#pragma unroll
            for (int ks = 0; ks < 2; ks++) {
                short8 a[4], b[4];
                int cc = ks * 4 + (lane >> 4);
#pragma unroll
                for (int m = 0; m < 4; m++) {
                    int R = wm * 64 + m * 16 + (lane & 15);
                    a[m] = *(const short8*)&As[R * 64 + ((cc ^ (R & 7)) * 8)];
                }
#pragma unroll
                for (int n = 0; n < 4; n++) {
                    int R = wn * 64 + n * 16 + (lane & 15);
                    b[n] = *(const short8*)&Bs[R * 64 + ((cc ^ (R & 7)) * 8)];
                }
#pragma unroll
                for (int m = 0; m < 4; m++)
#pragma unroll
                    for (int n = 0; n < 4; n++)
                        acc[m][n] = __builtin_amdgcn_mfma_f32_16x16x32_bf16(a[m], b[n], acc[m][n], 0, 0, 0);
            }
            __syncthreads();
        }

#pragma unroll
        for (int m = 0; m < 4; m++) {
#pragma unroll
            for (int j = 0; j < 4; j++) {
                int grow = row0 + wm * 64 + m * 16 + (lane >> 4) * 4 + j;
                if (grow >= M) continue;
                float dr = dis[list[grow]];
#pragma unroll
                for (int n = 0; n < 4; n++) {
                    int gcol = wn * 64 + n * 16 + (lane & 15);
                    float v = acc[m][n][j] + bias[gcol];
                    v = v > 0.f ? v : NEG_SLOPE * v;
                    C[(size_t)grow * 256 + gcol] = f2b(v * dr);
                }
            }
        }
    }
}

// ---------------- final: per graph, aggregate h2c at the root (via pos1), then 256x16 GEMM ----------------

__global__ __launch_bounds__(256) void final_c(const ushort* __restrict__ h2c,
                                               const float* __restrict__ dis,
                                               const int* __restrict__ rowptr,
                                               const int* __restrict__ col,
                                               const int* __restrict__ picked,
                                               const int* __restrict__ pos1,
                                               const float* __restrict__ W3,
                                               const float* __restrict__ b3,
                                               float* __restrict__ out, int G) {
    __shared__ float agg[256];
    __shared__ float red[256];
    int g = blockIdx.x;
    int t = threadIdx.x;
    if (g >= G) return;
    int i = picked[g];
    float di = dis[i];
    float a = b2f(h2c[(size_t)pos1[i] * 256 + t]);
    int e1 = rowptr[i + 1];
    for (int e = rowptr[i]; e < e1; e++) {
        a += b2f(h2c[(size_t)pos1[col[e]] * 256 + t]);
    }
    agg[t] = di * a;
    __syncthreads();
    int c = t & 15, seg = t >> 4;
    float p = 0.f;
#pragma unroll
    for (int kk = 0; kk < 16; kk++) {
        int k = seg * 16 + kk;
        p += agg[k] * W3[k * 16 + c];
    }
    red[t] = p;
    __syncthreads();
    if (t < 16) {
        float sres = 0.f;
#pragma unroll
        for (int ss = 0; ss < 16; ss++) sres += red[ss * 16 + t];
        out[g * 16 + t] = sres + b3[t];
    }
}

// ---------------- launch ----------------

extern "C" void kernel_launch(void* const* d_in, const int* in_sizes, int n_in,
                              void* d_out, int out_size, void* d_ws, size_t ws_size,
                              hipStream_t stream) {
    const float* x   = (const float*)d_in[0];
    const int* ei    = (const int*)d_in[1];
    const int* batch = (const int*)d_in[2];
    const float* W1  = (const float*)d_in[3];
    const float* b1  = (const float*)d_in[4];
    const float* W2  = (const float*)d_in[5];
    const float* b2  = (const float*)d_in[6];
    const float* W3  = (const float*)d_in[7];
    const float* b3  = (const float*)d_in[8];

    const int IN = 128, H = 256, OUT = 16;
    int N = in_sizes[0] / IN;
    int E = in_sizes[1] / 2;
    int G = out_size / OUT;
    const int* srcp = ei;
    const int* dstp = ei + E;

    char* p = (char*)d_ws;
    auto carve = [&](size_t bytes) {
        char* q = p;
        p += (bytes + 255) & ~(size_t)255;
        return q;
    };
    int*    cnt      = (int*)carve((size_t)N * 4);
    int*    flag1    = (int*)carve((size_t)N * 4);
    int*    flag2    = (int*)carve((size_t)N * 4);
    int*    rootflag = (int*)carve((size_t)N * 4);
    float*  dis    = (float*)carve((size_t)N * 4);
    int*    rowptr = (int*)carve(((size_t)N + 1) * 4);
    int*    cur    = (int*)carve((size_t)N * 4);
    int4*   aggslot= (int4*)carve(1024 * 16);
    int*    counts = (int*)carve(256);
    int*    picked = (int*)carve((size_t)G * 4);
    int*    pos1   = (int*)carve((size_t)N * 4);
    int*    pos2   = (int*)carve((size_t)N * 4);
    int*    list1  = (int*)carve((size_t)N * 4);
    int*    list2  = (int*)carve((size_t)N * 4);
    int*    col    = (int*)carve((size_t)E * 4);
    ushort* W1t    = (ushort*)carve((size_t)256 * 128 * 2);
    ushort* W2t    = (ushort*)carve((size_t)256 * 256 * 2);
    ushort* RA     = (ushort*)carve((size_t)N * H * 2);  // aggXc, then agg1c
    ushort* RB     = (ushort*)carve((size_t)N * H * 2);  // h1c, then h2c

    ushort* aggXc = RA;   // [M2][128]
    ushort* agg1c = RA;   // [M1][256] (aggXc dead after gemm1)
    ushort* h1c   = RB;   // [M2][256]
    ushort* h2c   = RB;   // [M1][256] (h1c dead after agg2)

    int nb = (N + 1023) / 1024;
    int e4 = (E + 3) / 4;
    int epN = (e4 > N ? e4 : N);

    // 1) init
    init_kernel<<<(N + 255) / 256, 256, 0, stream>>>(batch, cnt, flag1, flag2, rootflag,
                                                     picked, aggslot, N);
    // 2) degrees + frontier1
    count_f1<<<(e4 + 255) / 256, 256, 0, stream>>>(srcp, dstp, rootflag, cnt, flag1, E);
    // 3) frontier2
    frontier2v<<<(epN + 255) / 256, 256, 0, stream>>>(srcp, dstp, flag1, flag2, E, N);
    // 4) single-kernel triple scan (+dis +wtrans)
    scan_one<<<nb, 256, 0, stream>>>(cnt, flag1, flag2, aggslot, dis, rowptr, cur,
                                     pos1, pos2, list1, list2, counts, N, nb,
                                     W1, W1t, W2, W2t);
    // 5) filtered CSR fill
    fill_fv<<<(e4 + 255) / 256, 256, 0, stream>>>(srcp, dstp, flag2, cur, col, E);
    // 6) layer-1 aggregation on S2
    aggx_c<<<1024, 256, 0, stream>>>(x, dis, rowptr, col, list2, counts, aggXc);
    // 7) layer-1 GEMM
    gemm_c<128><<<128, 512, 0, stream>>>(aggXc, W1t, b1, dis, list2, counts, 1, h1c);
    // 8) layer-2 aggregation on S1
    agg2_c<<<128, 256, 0, stream>>>(h1c, dis, rowptr, col, list1, pos2, counts, agg1c);
    // 9) layer-2 GEMM
    gemm_c<256><<<64, 512, 0, stream>>>(agg1c, W2t, b2, dis, list1, counts, 0, h2c);
    // 10) final at roots
    final_c<<<G, 256, 0, stream>>>(h2c, dis, rowptr, col, picked, pos1, W3, b3, (float*)d_out, G);
}